// Round 3
// baseline (902.418 us; speedup 1.0000x reference)
//
#include <hip/hip_runtime.h>

// SimpleCA: fused toroidal depthwise 3x3 stencil + 1x1 MLP (4->6 relu ->4) + masked residual.
// NHWC, C=4 -> one float4 per pixel.
//
// R2 findings: kernel is LATENCY-bound, not BW-bound (2.4 TB/s, VALUBusy 23%,
// occupancy 68%, VGPR=36 -> compiler kept nothing in flight). R=16 + NT store
// regressed vs R=8. This version:
//  - R back to 8 (2M threads, TLP).
//  - Row summaries {t,u,v,center}: 7 floats/row instead of 12 -> frees VGPRs,
//    halves stencil VALU (t/u/v computed once per row, reused by 3 output rows).
//  - 2-row-deep double-buffered raw prefetch (static indices under full unroll)
//    + 1-row-early rnd prefetch: load-to-use distance ~2 iterations.
//  - Normal stores (fill kernels hit 6.5 TB/s through L2; NT store regressed).
//  - Keep chunked XCD swizzle (adjacent strips of one image share halo rows in
//    one XCD's L2; 1024-block chunks = 8 images per XCD).
//  - __launch_bounds__(256, 8): pin <=64 VGPR -> 8 waves/SIMD.

constexpr int H = 512, W = 512, C = 4, HIDN = 6, R = 8;
constexpr int NXCD = 8;

typedef float f32x4 __attribute__((ext_vector_type(4)));

struct RowSum { float t, u, v; f32x4 ctr; };

__device__ __forceinline__ f32x4 ld4(const float* p) {
    return *reinterpret_cast<const f32x4*>(p);
}

// Per-row stencil partials: t = sobel_x horizontal diff (ch y),
// u = 1-2-1 horizontal sum (ch z), v = 1-2-1 horizontal sum (ch w).
__device__ __forceinline__ RowSum reduce_row(f32x4 l, f32x4 c, f32x4 r) {
    RowSum s;
    s.t = r.y - l.y;
    s.u = __builtin_fmaf(2.f, c.z, l.z + r.z);
    s.v = __builtin_fmaf(2.f, c.w, l.w + r.w);
    s.ctr = c;
    return s;
}

__global__ __launch_bounds__(256, 8) void ca_kernel(
    const float* __restrict__ x,
    const float* __restrict__ rnd,
    const float* __restrict__ w1,
    const float* __restrict__ b1,
    const float* __restrict__ w2,
    float* __restrict__ out)
{
    // Chunked XCD swizzle (8192 blocks % 8 == 0 -> bijective).
    const int nblk  = (int)gridDim.x;
    const int chunk = nblk / NXCD;
    const int bid   = (int)blockIdx.x;
    const int swz   = (bid & (NXCD - 1)) * chunk + (bid >> 3);

    const int t = swz * (int)blockDim.x + (int)threadIdx.x;
    const int w     = t & (W - 1);             // lane-fast along W -> coalesced
    const int strip = t >> 9;                  // / W
    const int h0    = (strip & (H / R - 1)) * R;
    const int b     = strip >> 6;              // / (H/R) with H/R = 64

    const int wm = (w == 0) ? (W - 1) : (w - 1);
    const int wp = (w == W - 1) ? 0 : (w + 1);
    const int om = wm << 2, oc = w << 2, op = wp << 2;   // float offsets in a row

    // Weights: wave-uniform -> s_loads / SGPRs.
    float w1r[C * HIDN], b1r[HIDN], w2r[HIDN * C];
    #pragma unroll
    for (int i = 0; i < C * HIDN; ++i) w1r[i] = w1[i];
    #pragma unroll
    for (int i = 0; i < HIDN; ++i) b1r[i] = b1[i];
    #pragma unroll
    for (int i = 0; i < HIDN * C; ++i) w2r[i] = w2[i];

    const float* xb = x   + (size_t)b * H * W * C;
    const float* rb = rnd + (size_t)b * H * W;
    float*       ob = out + (size_t)b * H * W * C;

    // Summaries for rows h-1 (sa), h (sc), h+1 (sd); raw double-buffer for h+2/h+3.
    RowSum sa, sc, sd;
    f32x4 bl[2], bc[2], br[2];
    {
        const int hm = (h0 == 0) ? (H - 1) : (h0 - 1);
        const float* r0 = xb + (size_t)hm * (W * C);
        const float* r1 = xb + (size_t)h0 * (W * C);
        const float* r2 = xb + (size_t)(h0 + 1) * (W * C);
        const float* r3 = xb + (size_t)(h0 + 2) * (W * C);   // h0 <= H-8
        const float* r4 = xb + (size_t)(h0 + 3) * (W * C);
        sa = reduce_row(ld4(r0 + om), ld4(r0 + oc), ld4(r0 + op));
        sc = reduce_row(ld4(r1 + om), ld4(r1 + oc), ld4(r1 + op));
        sd = reduce_row(ld4(r2 + om), ld4(r2 + oc), ld4(r2 + op));
        bl[0] = ld4(r3 + om); bc[0] = ld4(r3 + oc); br[0] = ld4(r3 + op);
        bl[1] = ld4(r4 + om); bc[1] = ld4(r4 + oc); br[1] = ld4(r4 + op);
    }

    float rv_next = rb[h0 * W + w];   // rnd prefetch, one row ahead

    #pragma unroll
    for (int r = 0; r < R; ++r) {
        const int h = h0 + r;

        // Stencil outputs from row summaries.
        const float p0 = sc.ctr.x;                                   // identity
        const float p1 = (sa.t + sd.t) + 2.f * sc.t;                 // sobel_x
        const float p2 = sd.u - sa.u;                                // sobel_y
        const float p3 = (sa.v + sd.v) + 2.f * sc.v - 16.f * sc.ctr.w;  // laplacian

        float hid[HIDN];
        #pragma unroll
        for (int j = 0; j < HIDN; ++j) {
            float v = p0 * w1r[j] + p1 * w1r[HIDN + j] + p2 * w1r[2 * HIDN + j]
                    + p3 * w1r[3 * HIDN + j] + b1r[j];
            hid[j] = v > 0.f ? v : 0.f;
        }
        float dx0 = 0.f, dx1 = 0.f, dx2 = 0.f, dx3 = 0.f;
        #pragma unroll
        for (int j = 0; j < HIDN; ++j) {
            dx0 += hid[j] * w2r[j * 4 + 0];
            dx1 += hid[j] * w2r[j * 4 + 1];
            dx2 += hid[j] * w2r[j * 4 + 2];
            dx3 += hid[j] * w2r[j * 4 + 3];
        }

        const float mask = floorf(rv_next + 0.5f);   // exact ref semantics
        if (r < R - 1) rv_next = rb[(h + 1) * W + w];

        f32x4 o;
        o.x = sc.ctr.x + dx0 * mask;
        o.y = sc.ctr.y + dx1 * mask;
        o.z = sc.ctr.z + dx2 * mask;
        o.w = sc.ctr.w + dx3 * mask;
        *reinterpret_cast<f32x4*>(ob + ((h * W + w) << 2)) = o;

        if (r < R - 1) {
            sa = sc; sc = sd;
            const int ib = r & 1;                    // static after full unroll
            sd = reduce_row(bl[ib], bc[ib], br[ib]); // row h+2
            if (r <= R - 4) {                        // refill with row h+4
                int hn = h + 4;
                if (hn >= H) hn -= H;                // wraps only on last strip
                const float* rp = xb + (size_t)hn * (W * C);
                bl[ib] = ld4(rp + om);
                bc[ib] = ld4(rp + oc);
                br[ib] = ld4(rp + op);
            }
        }
    }
}

extern "C" void kernel_launch(void* const* d_in, const int* in_sizes, int n_in,
                              void* d_out, int out_size, void* d_ws, size_t ws_size,
                              hipStream_t stream) {
    const float* x   = (const float*)d_in[0];
    const float* rnd = (const float*)d_in[1];
    const float* w1  = (const float*)d_in[2];
    const float* b1  = (const float*)d_in[3];
    const float* w2  = (const float*)d_in[4];
    float* out = (float*)d_out;

    const int B = in_sizes[0] / (H * W * C);          // 64
    const int total_threads = B * (H / R) * W;        // 2,097,152
    dim3 grid(total_threads / 256), block(256);       // 8192 blocks, %8 == 0
    hipLaunchKernelGGL(ca_kernel, grid, block, 0, stream, x, rnd, w1, b1, w2, out);
}

// Round 4
// 491.554 us; speedup vs baseline: 1.8358x; 1.8358x over previous
//
#include <hip/hip_runtime.h>

// SimpleCA: fused toroidal depthwise 3x3 stencil + 1x1 MLP (4->6 relu ->4) + masked residual.
// NHWC, C=4 -> one float4 per pixel.
//
// R3 post-mortem: __launch_bounds__(256,8) capped VGPR at 32 -> everything
// spilled to scratch (FETCH 876MB, WRITE 1.2GB, 575us). The row-summary +
// prefetch structure itself passed correctness. R4 = R3 with the register
// clamp REMOVED (plain __launch_bounds__(256)); let the allocator take
// ~56-72 VGPRs at 4-6 waves/SIMD, which R0/R2 showed is plenty of TLP.
//  - R=8 (2M threads).
//  - Row summaries {t,u,v,center}: 7 floats/row instead of 12; t/u/v computed
//    once per row, reused by the 3 output rows that see it.
//  - 2-row-deep double-buffered raw prefetch (static indices under full
//    unroll) + 1-row-early rnd prefetch: load-to-use distance ~2 rows.
//  - Chunked XCD swizzle (8192 blocks % 8 == 0 -> bijective).
//  - Normal stores (NT store regressed in R2).

constexpr int H = 512, W = 512, C = 4, HIDN = 6, R = 8;
constexpr int NXCD = 8;

typedef float f32x4 __attribute__((ext_vector_type(4)));

struct RowSum { float t, u, v; f32x4 ctr; };

__device__ __forceinline__ f32x4 ld4(const float* p) {
    return *reinterpret_cast<const f32x4*>(p);
}

// Per-row stencil partials: t = sobel_x horizontal diff (ch y),
// u = 1-2-1 horizontal sum (ch z), v = 1-2-1 horizontal sum (ch w).
__device__ __forceinline__ RowSum reduce_row(f32x4 l, f32x4 c, f32x4 r) {
    RowSum s;
    s.t = r.y - l.y;
    s.u = __builtin_fmaf(2.f, c.z, l.z + r.z);
    s.v = __builtin_fmaf(2.f, c.w, l.w + r.w);
    s.ctr = c;
    return s;
}

__global__ __launch_bounds__(256) void ca_kernel(
    const float* __restrict__ x,
    const float* __restrict__ rnd,
    const float* __restrict__ w1,
    const float* __restrict__ b1,
    const float* __restrict__ w2,
    float* __restrict__ out)
{
    // Chunked XCD swizzle (8192 blocks % 8 == 0 -> bijective).
    const int nblk  = (int)gridDim.x;
    const int chunk = nblk / NXCD;
    const int bid   = (int)blockIdx.x;
    const int swz   = (bid & (NXCD - 1)) * chunk + (bid >> 3);

    const int t = swz * (int)blockDim.x + (int)threadIdx.x;
    const int w     = t & (W - 1);             // lane-fast along W -> coalesced
    const int strip = t >> 9;                  // / W
    const int h0    = (strip & (H / R - 1)) * R;
    const int b     = strip >> 6;              // / (H/R) with H/R = 64

    const int wm = (w == 0) ? (W - 1) : (w - 1);
    const int wp = (w == W - 1) ? 0 : (w + 1);
    const int om = wm << 2, oc = w << 2, op = wp << 2;   // float offsets in a row

    // Weights: wave-uniform -> s_loads / SGPRs.
    float w1r[C * HIDN], b1r[HIDN], w2r[HIDN * C];
    #pragma unroll
    for (int i = 0; i < C * HIDN; ++i) w1r[i] = w1[i];
    #pragma unroll
    for (int i = 0; i < HIDN; ++i) b1r[i] = b1[i];
    #pragma unroll
    for (int i = 0; i < HIDN * C; ++i) w2r[i] = w2[i];

    const float* xb = x   + (size_t)b * H * W * C;
    const float* rb = rnd + (size_t)b * H * W;
    float*       ob = out + (size_t)b * H * W * C;

    // Summaries for rows h-1 (sa), h (sc), h+1 (sd); raw double-buffer for h+2/h+3.
    RowSum sa, sc, sd;
    f32x4 bl[2], bc[2], br[2];
    {
        const int hm = (h0 == 0) ? (H - 1) : (h0 - 1);
        const float* r0 = xb + (size_t)hm * (W * C);
        const float* r1 = xb + (size_t)h0 * (W * C);
        const float* r2 = xb + (size_t)(h0 + 1) * (W * C);
        const float* r3 = xb + (size_t)(h0 + 2) * (W * C);   // h0 <= H-8
        const float* r4 = xb + (size_t)(h0 + 3) * (W * C);
        sa = reduce_row(ld4(r0 + om), ld4(r0 + oc), ld4(r0 + op));
        sc = reduce_row(ld4(r1 + om), ld4(r1 + oc), ld4(r1 + op));
        sd = reduce_row(ld4(r2 + om), ld4(r2 + oc), ld4(r2 + op));
        bl[0] = ld4(r3 + om); bc[0] = ld4(r3 + oc); br[0] = ld4(r3 + op);
        bl[1] = ld4(r4 + om); bc[1] = ld4(r4 + oc); br[1] = ld4(r4 + op);
    }

    float rv_next = rb[h0 * W + w];   // rnd prefetch, one row ahead

    #pragma unroll
    for (int r = 0; r < R; ++r) {
        const int h = h0 + r;

        // Stencil outputs from row summaries.
        const float p0 = sc.ctr.x;                                   // identity
        const float p1 = (sa.t + sd.t) + 2.f * sc.t;                 // sobel_x
        const float p2 = sd.u - sa.u;                                // sobel_y
        const float p3 = (sa.v + sd.v) + 2.f * sc.v - 16.f * sc.ctr.w;  // laplacian

        float hid[HIDN];
        #pragma unroll
        for (int j = 0; j < HIDN; ++j) {
            float v = p0 * w1r[j] + p1 * w1r[HIDN + j] + p2 * w1r[2 * HIDN + j]
                    + p3 * w1r[3 * HIDN + j] + b1r[j];
            hid[j] = v > 0.f ? v : 0.f;
        }
        float dx0 = 0.f, dx1 = 0.f, dx2 = 0.f, dx3 = 0.f;
        #pragma unroll
        for (int j = 0; j < HIDN; ++j) {
            dx0 += hid[j] * w2r[j * 4 + 0];
            dx1 += hid[j] * w2r[j * 4 + 1];
            dx2 += hid[j] * w2r[j * 4 + 2];
            dx3 += hid[j] * w2r[j * 4 + 3];
        }

        const float mask = floorf(rv_next + 0.5f);   // exact ref semantics
        if (r < R - 1) rv_next = rb[(h + 1) * W + w];

        f32x4 o;
        o.x = sc.ctr.x + dx0 * mask;
        o.y = sc.ctr.y + dx1 * mask;
        o.z = sc.ctr.z + dx2 * mask;
        o.w = sc.ctr.w + dx3 * mask;
        *reinterpret_cast<f32x4*>(ob + ((h * W + w) << 2)) = o;

        if (r < R - 1) {
            sa = sc; sc = sd;
            const int ib = r & 1;                    // static after full unroll
            sd = reduce_row(bl[ib], bc[ib], br[ib]); // row h+2
            if (r <= R - 4) {                        // refill with row h+4
                int hn = h + 4;
                if (hn >= H) hn -= H;                // wraps only on last strip
                const float* rp = xb + (size_t)hn * (W * C);
                bl[ib] = ld4(rp + om);
                bc[ib] = ld4(rp + oc);
                br[ib] = ld4(rp + op);
            }
        }
    }
}

extern "C" void kernel_launch(void* const* d_in, const int* in_sizes, int n_in,
                              void* d_out, int out_size, void* d_ws, size_t ws_size,
                              hipStream_t stream) {
    const float* x   = (const float*)d_in[0];
    const float* rnd = (const float*)d_in[1];
    const float* w1  = (const float*)d_in[2];
    const float* b1  = (const float*)d_in[3];
    const float* w2  = (const float*)d_in[4];
    float* out = (float*)d_out;

    const int B = in_sizes[0] / (H * W * C);          // 64
    const int total_threads = B * (H / R) * W;        // 2,097,152
    dim3 grid(total_threads / 256), block(256);       // 8192 blocks, %8 == 0
    hipLaunchKernelGGL(ca_kernel, grid, block, 0, stream, x, rnd, w1, b1, w2, out);
}